// Round 10
// baseline (122.828 us; speedup 1.0000x reference)
//
#include <hip/hip_runtime.h>
#include <hip/hip_bf16.h>

// SoftmaxLossRScore: mean(relu(logsumexp(A @ Neg^T, axis=1) - rowdot(A,P) + r + 1))
// B=2048, N=32768, D=128. bf16 MFMA fused GEMM+sumexp, no [B,N] materialization.
// A pre-scaled by log2(e) so epilogue is a bare v_exp_f32 (exp2).
// R2: XOR-swizzled LDS chunks (chunk ^= row&7) kill frag-read bank conflicts.
// R6: counted-vmcnt 4-slot ring (best measured: 95.29us total).
// Ledger: R3 setprio/STEP -29% | R4 reg-direct B -3x | R5 XCD remap -69% |
//   R7 3 blocks/CU -41% | R8 BM=256 neutral | R9 fine phases neutral |
//   R10 operand swap -28%. All schedule/geometry levers exhausted.
// R11: R6 verbatim + finalize folded in via last-block ticket (isolated from
//   R3's regression bundle; correctness-proven there). Saves one launch+gap.

#define B_ROWS 2048
#define N_NEG  32768
#define DIM    128
#define LOG2E  1.4426950408889634f
#define LN2    0.6931471805599453f

typedef __bf16 bf16x8 __attribute__((ext_vector_type(8)));
typedef float  f32x4  __attribute__((ext_vector_type(4)));

static __device__ inline unsigned short f2bf(float f) {
    union { float f; unsigned u; } v; v.f = f;
    unsigned r = v.u + 0x7FFF + ((v.u >> 16) & 1);   // round-to-nearest-even
    return (unsigned short)(r >> 16);
}

static __device__ inline void load_lds16(const void* g, void* s) {
    __builtin_amdgcn_global_load_lds(
        (const __attribute__((address_space(1))) void*)g,
        (__attribute__((address_space(3))) void*)s,
        16, 0, 0);
}

// ---------- P1 (merged): anchor->bf16*log2e + pos_sim + zero sumexp, neg->bf16
__global__ void prep(const float* __restrict__ anchor,
                     const float* __restrict__ positive,
                     const float* __restrict__ neg,
                     unsigned short* __restrict__ a_bf,
                     unsigned short* __restrict__ n_bf,
                     float* __restrict__ pos_sim,
                     float* __restrict__ sumexp,
                     unsigned* __restrict__ counter) {
    int t = threadIdx.x;
    if (blockIdx.x == 0 && t == 0) counter[0] = 0;
    if (blockIdx.x < 256) {
        int row = blockIdx.x * 8 + (t >> 5);
        int c4  = (t & 31) * 4;
        const float4 a4 = *(const float4*)(anchor   + row * DIM + c4);
        const float4 p4 = *(const float4*)(positive + row * DIM + c4);
        float dot = a4.x * p4.x + a4.y * p4.y + a4.z * p4.z + a4.w * p4.w;
        ushort4 ab;
        ab.x = f2bf(a4.x * LOG2E); ab.y = f2bf(a4.y * LOG2E);
        ab.z = f2bf(a4.z * LOG2E); ab.w = f2bf(a4.w * LOG2E);
        *(ushort4*)(a_bf + row * DIM + c4) = ab;
        #pragma unroll
        for (int m = 1; m <= 16; m <<= 1) dot += __shfl_xor(dot, m, 64);
        if ((t & 31) == 0) { pos_sim[row] = dot; sumexp[row] = 0.0f; }
    } else {
        int i = (blockIdx.x - 256) * 256 + t;   // float4 index
        #pragma unroll
        for (int k = 0; k < 4; k++) {
            int idx = i + k * (1024 * 256);
            float4 v = *(const float4*)(neg + (size_t)idx * 4);
            ushort4 o;
            o.x = f2bf(v.x); o.y = f2bf(v.y); o.z = f2bf(v.z); o.w = f2bf(v.w);
            *(ushort4*)(n_bf + (size_t)idx * 4) = o;
        }
    }
}

// ---------- main: fused bf16 GEMM + sum(exp2) + last-block finalize ----------
// Grid 512 = 16 row-tiles x 32 N-chunks, natural bid order. Block 256 thr =
// 4 waves (2x2). Block tile 128 rows x 1024 cols, inner BN=128. A-frags
// register-resident. LDS 64 KB = ring of 4 slots x 16 KB (64 B-rows each).
// Tile t occupies slots {(2t+2)&3,(2t+3)&3}; wave (wr,wc) reads half wc.
// Counted vmcnt: next tile's 8 loads stay in flight across raw s_barriers.
// LDS rows are 256 B; 16B chunk j of row r holds global chunk j^(r&7)
// (swizzle applied on the global source address; DMA dest stays linear).
#define CHUNK 1024
#define TSTEPS (CHUNK / 128)   // 8

__global__ __launch_bounds__(256, 2) void fused_gemm_lse(
        const unsigned short* __restrict__ A,
        const unsigned short* __restrict__ Nb,
        float* __restrict__ sumexp,
        const float* __restrict__ pos_sim,
        const float* __restrict__ r_score,
        unsigned* __restrict__ counter,
        float* __restrict__ out) {
    __shared__ unsigned short lds[4 * 8192];   // 64 KB ring
    __shared__ unsigned lastTicket;
    __shared__ float red[4];

    const int bid     = blockIdx.x;
    const int rowTile = bid & 15;
    const int chunk   = bid >> 4;
    const int wave = threadIdx.x >> 6, lane = threadIdx.x & 63;
    const int wr = wave >> 1, wc = wave & 1;
    const int q = lane >> 4, c = lane & 15;
    const int lrow = lane >> 4;       // staging: row within 4-row group
    const int lchk = lane & 15;       // staging: 16B chunk within row

    const unsigned short* Ag = A + rowTile * (128 * DIM);
    const unsigned short* Bg = Nb + (size_t)(chunk * CHUNK) * DIM;

// stage one 128-row tile at gbase into the ring slots of tile index (tt):
// half h -> slot (2*tt+2+h)&3. Wave w stages rows (w&1)*32..+31 of half w>>1.
#define STAGE_TILE(gbase, tt)                                                  \
    {                                                                          \
        const int h_ = wave >> 1;                                              \
        const int s_ = (2 * (tt) + 2 + h_) & 3;                                \
        _Pragma("unroll")                                                      \
        for (int i_ = 0; i_ < 8; i_++) {                                       \
            int rloc_ = (wave & 1) * 32 + i_ * 4;       /* uniform base row */ \
            int rg_   = h_ * 64 + rloc_ + lrow;         /* per-lane tile row */\
            int gofs_ = rg_ * DIM + ((lchk ^ (rg_ & 7)) << 3);                 \
            load_lds16((gbase) + gofs_, &lds[s_ * 8192 + rloc_ * DIM]);        \
        }                                                                      \
    }

    // ---- prologue: A -> slots {0,1}, B(0) -> slots {2,3} ----
    STAGE_TILE(Ag, -1);                    // slots h (= {0,1})
    STAGE_TILE(Bg, 0);                     // slots {2,3}
    asm volatile("s_waitcnt vmcnt(8)" ::: "memory");   // A landed, B0 in flight
    __builtin_amdgcn_s_barrier();

    // swizzled k-step chunk offsets (ushort units); fragment rows are == c
    // mod 8 everywhere, so this is invariant across t/j/i.
    int swz[4];
    #pragma unroll
    for (int k = 0; k < 4; k++) swz[k] = (((k * 4 + q) ^ (c & 7)) << 3);

    // preload A fragments: wave rows wr*64..+64 live in slot wr
    bf16x8 af[4][4];
    #pragma unroll
    for (int i = 0; i < 4; i++) {
        int row = i * 16 + c;              // row within the 64-row half
        #pragma unroll
        for (int k = 0; k < 4; k++)
            af[i][k] = *(const bf16x8*)&lds[wr * 8192 + row * DIM + swz[k]];
    }
    asm volatile("s_waitcnt lgkmcnt(0)" ::: "memory");
    __builtin_amdgcn_s_barrier();          // af reads done; slots {0,1} free

    STAGE_TILE(Bg + 128 * DIM, 1);         // B(1) -> slots {0,1}

    const f32x4 zero4 = {0.f, 0.f, 0.f, 0.f};
    f32x4 sumacc[4] = {zero4, zero4, zero4, zero4};

    for (int t = 0; t < TSTEPS; t++) {
        // wait: current tile's loads landed; next tile's 8 stay in flight
        if (t < TSTEPS - 1) asm volatile("s_waitcnt vmcnt(8)" ::: "memory");
        else                asm volatile("s_waitcnt vmcnt(0)" ::: "memory");
        __builtin_amdgcn_s_barrier();

        const int sb = (2 * t + 2 + wc) & 3;   // this wave's B half-slot
        #pragma unroll
        for (int j = 0; j < 4; j++) {          // 4 j-tiles of 16 cols
            int brow = j * 16 + c;             // row within the half
            bf16x8 bf[4];
            #pragma unroll
            for (int k = 0; k < 4; k++)
                bf[k] = *(const bf16x8*)&lds[sb * 8192 + brow * DIM + swz[k]];
            #pragma unroll
            for (int i = 0; i < 4; i++) {
                f32x4 acc = __builtin_amdgcn_mfma_f32_16x16x32_bf16(af[i][0], bf[0], zero4, 0, 0, 0);
                acc = __builtin_amdgcn_mfma_f32_16x16x32_bf16(af[i][1], bf[1], acc, 0, 0, 0);
                acc = __builtin_amdgcn_mfma_f32_16x16x32_bf16(af[i][2], bf[2], acc, 0, 0, 0);
                acc = __builtin_amdgcn_mfma_f32_16x16x32_bf16(af[i][3], bf[3], acc, 0, 0, 0);
                sumacc[i][0] += __builtin_amdgcn_exp2f(acc[0]);
                sumacc[i][1] += __builtin_amdgcn_exp2f(acc[1]);
                sumacc[i][2] += __builtin_amdgcn_exp2f(acc[2]);
                sumacc[i][3] += __builtin_amdgcn_exp2f(acc[3]);
            }
        }
        asm volatile("s_waitcnt lgkmcnt(0)" ::: "memory");
        __builtin_amdgcn_s_barrier();          // all reads of tile t done
        if (t + 2 < TSTEPS)                    // overwrite tile t's slots
            STAGE_TILE(Bg + (size_t)(t + 2) * 128 * DIM, t + 2);
    }
#undef STAGE_TILE

    // per-row combine: reduce 16 column-lanes, atomic into global
    #pragma unroll
    for (int i = 0; i < 4; i++) {
        #pragma unroll
        for (int r = 0; r < 4; r++) {
            float v = sumacc[i][r];
            v += __shfl_xor(v, 1, 64);
            v += __shfl_xor(v, 2, 64);
            v += __shfl_xor(v, 4, 64);
            v += __shfl_xor(v, 8, 64);
            if ((lane & 15) == 0) {
                int row = rowTile * 128 + wr * 64 + i * 16 + q * 4 + r;
                atomicAdd(&sumexp[row], v);
            }
        }
    }

    // ---- last-block finalize: lse, relu, mean -> scalar (saves a launch) ----
    __threadfence();
    __syncthreads();
    if (threadIdx.x == 0) lastTicket = atomicAdd(counter, 1u);
    __syncthreads();
    if (lastTicket == 511) {
        int t = threadIdx.x;
        float acc = 0.0f;
        #pragma unroll
        for (int i = 0; i < 8; i++) {
            int row = t + i * 256;
            float se = __hip_atomic_load(&sumexp[row], __ATOMIC_RELAXED,
                                         __HIP_MEMORY_SCOPE_AGENT);
            float lse  = __log2f(se) * LN2;   // A was pre-scaled by log2e
            float loss = lse - pos_sim[row] + r_score[row] + 1.0f;
            acc += fmaxf(loss, 0.0f);
        }
        #pragma unroll
        for (int m = 1; m <= 32; m <<= 1) acc += __shfl_xor(acc, m, 64);
        if ((t & 63) == 0) red[t >> 6] = acc;
        __syncthreads();
        if (t == 0)
            out[0] = (red[0] + red[1] + red[2] + red[3]) * (1.0f / (float)B_ROWS);
    }
}

extern "C" void kernel_launch(void* const* d_in, const int* in_sizes, int n_in,
                              void* d_out, int out_size, void* d_ws, size_t ws_size,
                              hipStream_t stream) {
    const float* anchor   = (const float*)d_in[0];
    const float* positive = (const float*)d_in[1];
    const float* negative = (const float*)d_in[2];
    const float* r_score  = (const float*)d_in[3];
    float* out = (float*)d_out;

    char* ws = (char*)d_ws;
    float* sumexp           = (float*)ws;                        // 2048 f32
    float* pos_sim          = (float*)(ws + 8192);               // 2048 f32
    unsigned* counter       = (unsigned*)(ws + 16384);           // 1 u32
    unsigned short* a_bf    = (unsigned short*)(ws + 20480);     // 512 KB
    unsigned short* n_bf    = (unsigned short*)(ws + 20480 + 524288); // 8 MB

    prep<<<1280, 256, 0, stream>>>(anchor, positive, negative, a_bf, n_bf,
                                   pos_sim, sumexp, counter);
    fused_gemm_lse<<<512, 256, 0, stream>>>(a_bf, n_bf, sumexp, pos_sim,
                                            r_score, counter, out);
}

// Round 11
// 100.494 us; speedup vs baseline: 1.2222x; 1.2222x over previous
//
#include <hip/hip_runtime.h>
#include <hip/hip_bf16.h>

// SoftmaxLossRScore: mean(relu(logsumexp(A @ Neg^T, axis=1) - rowdot(A,P) + r + 1))
// B=2048, N=32768, D=128. bf16 MFMA fused GEMM+sumexp, no [B,N] materialization.
// A pre-scaled by log2(e) so epilogue is a bare v_exp_f32 (exp2).
// Ledger: R3 setprio/STEP -29% | R4 reg-direct B -3x | R5 XCD remap -69% |
//   R6 counted-vmcnt ring (95.29, best) | R7 3 blk/CU -41% | R8 BM=256 neut |
//   R9 fine phases neut | R10 operand swap -28% | R11 finalize fold -29%
//   (the __threadfence per block IS the cost; fold dead).
// R12: fused kernel = R6 skeleton (natural bid order, counted vmcnt, XOR
//   swizzle, 2 blocks/CU) but stages NEGATIVE AS F32 DIRECTLY (64-col tiles,
//   32KB dbuf; f32->bf16 cast during LDS->reg frag assembly). Kills the 8MB
//   n_bf intermediate: -16MB HBM traffic and prep shrinks to the 256-block
//   anchor pass (~24MB pass + 1024-block ramp removed).

#define B_ROWS 2048
#define N_NEG  32768
#define DIM    128
#define LOG2E  1.4426950408889634f
#define LN2    0.6931471805599453f

typedef __bf16 bf16x8 __attribute__((ext_vector_type(8)));
typedef float  f32x4  __attribute__((ext_vector_type(4)));

static __device__ inline unsigned short f2bf(float f) {
    union { float f; unsigned u; } v; v.f = f;
    unsigned r = v.u + 0x7FFF + ((v.u >> 16) & 1);   // round-to-nearest-even
    return (unsigned short)(r >> 16);
}

static __device__ inline void load_lds16(const void* g, void* s) {
    __builtin_amdgcn_global_load_lds(
        (const __attribute__((address_space(1))) void*)g,
        (__attribute__((address_space(3))) void*)s,
        16, 0, 0);
}

// ---------- P1: anchor->bf16*log2e + pos_sim + zero sumexp (256 blocks) -----
__global__ void prep(const float* __restrict__ anchor,
                     const float* __restrict__ positive,
                     unsigned short* __restrict__ a_bf,
                     float* __restrict__ pos_sim,
                     float* __restrict__ sumexp) {
    int t = threadIdx.x;
    int row = blockIdx.x * 8 + (t >> 5);
    int c4  = (t & 31) * 4;
    const float4 a4 = *(const float4*)(anchor   + row * DIM + c4);
    const float4 p4 = *(const float4*)(positive + row * DIM + c4);
    float dot = a4.x * p4.x + a4.y * p4.y + a4.z * p4.z + a4.w * p4.w;
    ushort4 ab;
    ab.x = f2bf(a4.x * LOG2E); ab.y = f2bf(a4.y * LOG2E);
    ab.z = f2bf(a4.z * LOG2E); ab.w = f2bf(a4.w * LOG2E);
    *(ushort4*)(a_bf + row * DIM + c4) = ab;
    #pragma unroll
    for (int m = 1; m <= 16; m <<= 1) dot += __shfl_xor(dot, m, 64);
    if ((t & 31) == 0) { pos_sim[row] = dot; sumexp[row] = 0.0f; }
}

// ---------- main: fused bf16 GEMM + sum(exp2), B staged as f32 --------------
// Grid 512 = 16 row-tiles x 32 N-chunks, natural bid order. Block 256 thr =
// 4 waves (2 row x 2 col). Block tile 128 rows x 1024 cols; 16 t-steps of 64
// cols. B tile: 64 rows x 128 f32 = 32 KB, double-buffered (64 KB LDS); A
// (bf16 from prep) staged once through buf0, then register-resident af[4][4].
// Counted vmcnt(8): 8 staging loads/wave/tile, next tile's stay in flight.
// f32 swizzle: rows are 512 B = 32 x 16B chunks; LDS slot j of row r holds
// global chunk j^(r&7) (involution; applied on the global source address).
// Frag k of col-row brow = global chunks {8k+2q, 8k+2q+1} -> LDS slots
// (8k+2q)^(c&7) and that ^1; f32->bf16 cast during assembly.
#define CHUNK 1024
#define TSTEPS (CHUNK / 64)   // 16

__global__ __launch_bounds__(256, 2) void fused_gemm_lse(
        const unsigned short* __restrict__ A,
        const float* __restrict__ Neg,
        float* __restrict__ sumexp) {
    __shared__ unsigned short lds[2 * 16384];   // 64 KB: two 32 KB B buffers

    const int bid     = blockIdx.x;
    const int rowTile = bid & 15;
    const int chunk   = bid >> 4;
    const int wave = threadIdx.x >> 6, lane = threadIdx.x & 63;
    const int wr = wave >> 1, wc = wave & 1;
    const int q = lane >> 4, c = lane & 15;
    const int lrow = lane >> 4;       // A staging: row within 4-row group
    const int lchk = lane & 15;       // A staging: 16B chunk within row

    const unsigned short* Ag = A + rowTile * (128 * DIM);
    const float* Bg = Neg + (size_t)(chunk * CHUNK) * DIM;

// stage one 64-row f32 B tile (32 KB) at tile index tt into buffer bsel.
// Wave w covers rows w*16..+15: 8 loads of 2 rows (1 KB) each. Per-lane
// global chunk = slot ^ (r&7); LDS dest linear (DMA base + lane*16).
#define STAGE_B(tt, bsel)                                                      \
    {                                                                          \
        const float* Gt_ = Bg + (size_t)(tt) * 64 * DIM;                       \
        _Pragma("unroll")                                                      \
        for (int i_ = 0; i_ < 8; i_++) {                                       \
            int rbase_ = wave * 16 + i_ * 2;            /* uniform 2-row base */\
            int r_     = rbase_ + (lane >> 5);                                 \
            int slot_  = lane & 31;                                            \
            int gofs_  = r_ * DIM + ((slot_ ^ (r_ & 7)) << 2);                 \
            load_lds16(Gt_ + gofs_, &lds[(bsel) * 16384 + rbase_ * 256]);      \
        }                                                                      \
    }

    // ---- prologue: A (32 KB bf16) -> buf0, read frags, then B(0),B(1) ----
    #pragma unroll
    for (int i = 0; i < 8; i++) {
        int off = wave * 4096 + i * 512;            // ushort offset, 4 rows
        int r   = (off >> 7) + lrow;
        int gofs = r * DIM + ((lchk ^ (r & 7)) << 3);
        load_lds16(Ag + gofs, &lds[off]);
    }
    asm volatile("s_waitcnt vmcnt(0)" ::: "memory");
    __builtin_amdgcn_s_barrier();

    // bf16 A swizzle chunk offsets (ushort units); A frag rows == c (mod 8)
    int swz[4];
    #pragma unroll
    for (int k = 0; k < 4; k++) swz[k] = (((k * 4 + q) ^ (c & 7)) << 3);

    bf16x8 af[4][4];
    #pragma unroll
    for (int i = 0; i < 4; i++) {
        int row = wr * 64 + i * 16 + c;
        #pragma unroll
        for (int k = 0; k < 4; k++)
            af[i][k] = *(const bf16x8*)&lds[row * DIM + swz[k]];
    }
    asm volatile("s_waitcnt lgkmcnt(0)" ::: "memory");
    __builtin_amdgcn_s_barrier();          // af done; buf0 free for B

    STAGE_B(0, 0);
    STAGE_B(1, 1);

    const f32x4 zero4 = {0.f, 0.f, 0.f, 0.f};
    f32x4 sumacc[4] = {zero4, zero4, zero4, zero4};

    for (int t = 0; t < TSTEPS; t++) {
        // B(t)'s 8 loads landed; B(t+1)'s 8 stay in flight
        if (t < TSTEPS - 1) asm volatile("s_waitcnt vmcnt(8)" ::: "memory");
        else                asm volatile("s_waitcnt vmcnt(0)" ::: "memory");
        __builtin_amdgcn_s_barrier();

        const int bb = (t & 1) * 16384;        // current buffer (ushort units)
        #pragma unroll
        for (int j = 0; j < 2; j++) {          // wave cols = wc*32 + j*16
            int brow = wc * 32 + j * 16 + c;
            bf16x8 bf[4];
            #pragma unroll
            for (int k = 0; k < 4; k++) {
                int slotA = (8 * k + 2 * q) ^ (c & 7);
                const float4 fA = *(const float4*)&lds[bb + brow * 256 + slotA * 8];
                const float4 fB = *(const float4*)&lds[bb + brow * 256 + (slotA ^ 1) * 8];
                bf16x8 f;
                f[0] = (__bf16)fA.x; f[1] = (__bf16)fA.y;
                f[2] = (__bf16)fA.z; f[3] = (__bf16)fA.w;
                f[4] = (__bf16)fB.x; f[5] = (__bf16)fB.y;
                f[6] = (__bf16)fB.z; f[7] = (__bf16)fB.w;
                bf[k] = f;
            }
            #pragma unroll
            for (int i = 0; i < 4; i++) {
                f32x4 acc = __builtin_amdgcn_mfma_f32_16x16x32_bf16(af[i][0], bf[0], zero4, 0, 0, 0);
                acc = __builtin_amdgcn_mfma_f32_16x16x32_bf16(af[i][1], bf[1], acc, 0, 0, 0);
                acc = __builtin_amdgcn_mfma_f32_16x16x32_bf16(af[i][2], bf[2], acc, 0, 0, 0);
                acc = __builtin_amdgcn_mfma_f32_16x16x32_bf16(af[i][3], bf[3], acc, 0, 0, 0);
                sumacc[i][0] += __builtin_amdgcn_exp2f(acc[0]);
                sumacc[i][1] += __builtin_amdgcn_exp2f(acc[1]);
                sumacc[i][2] += __builtin_amdgcn_exp2f(acc[2]);
                sumacc[i][3] += __builtin_amdgcn_exp2f(acc[3]);
            }
        }
        asm volatile("s_waitcnt lgkmcnt(0)" ::: "memory");
        __builtin_amdgcn_s_barrier();          // all reads of buf(t&1) done
        if (t + 2 < TSTEPS) STAGE_B(t + 2, t & 1);
    }
#undef STAGE_B

    // per-row combine: reduce 16 column-lanes, atomic into global
    #pragma unroll
    for (int i = 0; i < 4; i++) {
        #pragma unroll
        for (int r = 0; r < 4; r++) {
            float v = sumacc[i][r];
            v += __shfl_xor(v, 1, 64);
            v += __shfl_xor(v, 2, 64);
            v += __shfl_xor(v, 4, 64);
            v += __shfl_xor(v, 8, 64);
            if ((lane & 15) == 0) {
                int row = rowTile * 128 + wr * 64 + i * 16 + q * 4 + r;
                atomicAdd(&sumexp[row], v);
            }
        }
    }
}

// ---------- final: lse, relu, mean -> scalar --------------------------------
__global__ void finalize(const float* __restrict__ sumexp,
                         const float* __restrict__ pos_sim,
                         const float* __restrict__ r_score,
                         float* __restrict__ out) {
    __shared__ float red[4];
    int t = threadIdx.x;
    float acc = 0.0f;
    #pragma unroll
    for (int i = 0; i < 8; i++) {
        int row = t + i * 256;
        float lse  = __log2f(sumexp[row]) * LN2;   // A was pre-scaled by log2e
        float loss = lse - pos_sim[row] + r_score[row] + 1.0f;
        acc += fmaxf(loss, 0.0f);
    }
    #pragma unroll
    for (int m = 1; m <= 32; m <<= 1) acc += __shfl_xor(acc, m, 64);
    if ((t & 63) == 0) red[t >> 6] = acc;
    __syncthreads();
    if (t == 0) out[0] = (red[0] + red[1] + red[2] + red[3]) * (1.0f / (float)B_ROWS);
}

extern "C" void kernel_launch(void* const* d_in, const int* in_sizes, int n_in,
                              void* d_out, int out_size, void* d_ws, size_t ws_size,
                              hipStream_t stream) {
    const float* anchor   = (const float*)d_in[0];
    const float* positive = (const float*)d_in[1];
    const float* negative = (const float*)d_in[2];
    const float* r_score  = (const float*)d_in[3];
    float* out = (float*)d_out;

    char* ws = (char*)d_ws;
    float* sumexp           = (float*)ws;                       // 2048 f32
    float* pos_sim          = (float*)(ws + 8192);              // 2048 f32
    unsigned short* a_bf    = (unsigned short*)(ws + 16384);    // 512 KB

    prep<<<256, 256, 0, stream>>>(anchor, positive, a_bf, pos_sim, sumexp);
    fused_gemm_lse<<<512, 256, 0, stream>>>(a_bf, negative, sumexp);
    finalize<<<1, 256, 0, stream>>>(sumexp, pos_sim, r_score, out);
}